// Round 3
// baseline (354.679 us; speedup 1.0000x reference)
//
#include <hip/hip_runtime.h>

#define DIM  128
#define SREF 10
#define ROWS_OUT 248  // output rows per block (2.8% overlap redundancy)
#define NPASS 32      // 32 passes x 8 row-slots = 256 score rows, covering [base-7, base+248]
#define ROWS_CMP (NPASS * 8)

// Fused: per-block stats (L2-fed, redundant) -> 32-lane-per-row summed-pdf
// scores -> 8-step windowed recurrence (carry beyond 8 steps weighs
// 128^-8 ~ 1.4e-17, below f32 ulp) -> normalize.
__global__ __launch_bounds__(256) void fused_kernel(const float* __restrict__ enc,
                                                    const float* __restrict__ nd,
                                                    const float* __restrict__ ad,
                                                    float2* __restrict__ out,
                                                    int n) {
    __shared__ float4 p4[6 * 32];       // [mu_n | b_n | c_n | mu_a | b_a | c_a] x 128 floats
    __shared__ float2 sc[ROWS_CMP];

    const int tid = threadIdx.x;
    const float INV_SQRT_2PI = 0.3989422804014327f;

    // ---- phase 0: stats (threads 0..127) ----
    if (tid < DIM) {
        float* pf = (float*)p4;
        {
            float v[SREF]; float s = 0.f;
            #pragma unroll
            for (int j = 0; j < SREF; ++j) { v[j] = nd[tid * SREF + j]; s += v[j]; }
            float mu = s * (1.0f / SREF);
            float var = 0.f;
            #pragma unroll
            for (int j = 0; j < SREF; ++j) { float t = v[j] - mu; var = fmaf(t, t, var); }
            var *= (1.0f / (SREF - 1));
            pf[tid]           = mu;
            pf[DIM + tid]     = -0.5f / var;
            pf[2 * DIM + tid] = INV_SQRT_2PI / sqrtf(var);
        }
        {
            float v[SREF]; float s = 0.f;
            #pragma unroll
            for (int j = 0; j < SREF; ++j) { v[j] = ad[tid * SREF + j]; s += v[j]; }
            float mu = s * (1.0f / SREF);
            float var = 0.f;
            #pragma unroll
            for (int j = 0; j < SREF; ++j) { float t = v[j] - mu; var = fmaf(t, t, var); }
            var *= (1.0f / (SREF - 1));
            pf[3 * DIM + tid] = mu;
            pf[4 * DIM + tid] = -0.5f / var;
            pf[5 * DIM + tid] = INV_SQRT_2PI / sqrtf(var);
        }
    }
    __syncthreads();

    const int lane = tid & 31;
    const int slot = tid >> 5;
    const long base = (long)blockIdx.x * ROWS_OUT;

    const float4 mu_n = p4[       lane];
    const float4 b_n  = p4[ 32 +  lane];
    const float4 c_n  = p4[ 64 +  lane];
    const float4 mu_a = p4[ 96 +  lane];
    const float4 b_a  = p4[128 +  lane];
    const float4 c_a  = p4[160 +  lane];

#define PDF_ACC(comp)                                                          \
    {                                                                          \
        float dn = x.comp - mu_n.comp;                                         \
        sn = fmaf(c_n.comp, __expf(b_n.comp * dn * dn), sn);                   \
        float da = x.comp - mu_a.comp;                                         \
        sa = fmaf(c_a.comp, __expf(b_a.comp * da * da), sa);                   \
    }

    // ---- phase B: scores for rows [base-7, base+ROWS_OUT] ----
    if (base >= 7 && base + ROWS_CMP - 7 <= n) {
        // interior fast path: no bounds checks in the hot loop
        const float4* ep = (const float4*)enc + (base - 7) * 32 + lane;
        #pragma unroll 4
        for (int p = 0; p < NPASS; ++p) {
            const int idx = p * 8 + slot;
            const float4 x = ep[idx * 32];
            float sn = 0.f, sa = 0.f;
            PDF_ACC(x) PDF_ACC(y) PDF_ACC(z) PDF_ACC(w)
            #pragma unroll
            for (int m = 16; m >= 1; m >>= 1) {
                sn += __shfl_xor(sn, m, 32);
                sa += __shfl_xor(sa, m, 32);
            }
            if (lane == 0) sc[idx] = make_float2(sn, sa);
        }
    } else {
        #pragma unroll 4
        for (int p = 0; p < NPASS; ++p) {
            const int idx = p * 8 + slot;
            const long g = base - 7 + idx;
            float sn = 0.f, sa = 0.f;
            if (g >= 0 && g < n) {
                const float4 x = ((const float4*)enc)[g * 32 + lane];
                PDF_ACC(x) PDF_ACC(y) PDF_ACC(z) PDF_ACC(w)
            }
            #pragma unroll
            for (int m = 16; m >= 1; m >>= 1) {
                sn += __shfl_xor(sn, m, 32);
                sa += __shfl_xor(sa, m, 32);
            }
            if (lane == 0) sc[idx] = make_float2(sn, sa);
        }
    }
#undef PDF_ACC
    __syncthreads();

    // ---- phase C: windowed scan + normalize (thread t -> row base+t) ----
    if (tid < ROWS_OUT) {
        const long r = base + tid;
        if (r < n) {
            const float inv_dim = 1.0f / 128.0f;
            float pn = 0.f, pa = 0.f;
            // sc[tid + k] holds s[r - 7 + k]; leading zero rows (r<7) reproduce
            // the reference's shorter window exactly (zeros are fixed points).
            #pragma unroll
            for (int k = 0; k < 8; ++k) {
                const float2 sv = sc[tid + k];
                pn = (pn + sv.x) * inv_dim;
                pa = (pa + sv.y) * inv_dim;
            }
            const float tot = pn + pa;
            out[r] = make_float2(pn / tot, pa / tot);
        }
    }
}

extern "C" void kernel_launch(void* const* d_in, const int* in_sizes, int n_in,
                              void* d_out, int out_size, void* d_ws, size_t ws_size,
                              hipStream_t stream) {
    const float* enc = (const float*)d_in[0];
    const float* nd  = (const float*)d_in[1];
    const float* ad  = (const float*)d_in[2];
    const int n_rows = in_sizes[0] / DIM;

    fused_kernel<<<(n_rows + ROWS_OUT - 1) / ROWS_OUT, 256, 0, stream>>>(
        enc, nd, ad, (float2*)d_out, n_rows);
}

// Round 4
// 346.631 us; speedup vs baseline: 1.0232x; 1.0232x over previous
//
#include <hip/hip_runtime.h>

#define DIM  128
#define SREF 10
#define ROWS_OUT 64   // output rows per block — best measured (R2); bigger tiles regressed (R3)
#define NPASS 9       // 9 passes x 8 row-slots = 72 score rows, covering [base-7, base+64]
#define ROWS_CMP (NPASS * 8)

// Fused: per-block stats (L2-fed, redundant) -> 32-lane-per-row summed-pdf
// scores -> 8-step windowed recurrence (carry beyond 8 steps weighs
// 128^-8 ~ 1.4e-17, below f32 ulp) -> normalize.
__global__ __launch_bounds__(256) void fused_kernel(const float* __restrict__ enc,
                                                    const float* __restrict__ nd,
                                                    const float* __restrict__ ad,
                                                    float2* __restrict__ out,
                                                    int n) {
    __shared__ float4 p4[6 * 32];       // [mu_n | b_n | c_n | mu_a | b_a | c_a] x 128 floats
    __shared__ float2 sc[ROWS_CMP];

    const int tid = threadIdx.x;
    const float INV_SQRT_2PI = 0.3989422804014327f;

    // ---- phase 0: stats (threads 0..127) ----
    if (tid < DIM) {
        float* pf = (float*)p4;
        {
            float v[SREF]; float s = 0.f;
            #pragma unroll
            for (int j = 0; j < SREF; ++j) { v[j] = nd[tid * SREF + j]; s += v[j]; }
            float mu = s * (1.0f / SREF);
            float var = 0.f;
            #pragma unroll
            for (int j = 0; j < SREF; ++j) { float t = v[j] - mu; var = fmaf(t, t, var); }
            var *= (1.0f / (SREF - 1));
            pf[tid]           = mu;
            pf[DIM + tid]     = -0.5f / var;
            pf[2 * DIM + tid] = INV_SQRT_2PI / sqrtf(var);
        }
        {
            float v[SREF]; float s = 0.f;
            #pragma unroll
            for (int j = 0; j < SREF; ++j) { v[j] = ad[tid * SREF + j]; s += v[j]; }
            float mu = s * (1.0f / SREF);
            float var = 0.f;
            #pragma unroll
            for (int j = 0; j < SREF; ++j) { float t = v[j] - mu; var = fmaf(t, t, var); }
            var *= (1.0f / (SREF - 1));
            pf[3 * DIM + tid] = mu;
            pf[4 * DIM + tid] = -0.5f / var;
            pf[5 * DIM + tid] = INV_SQRT_2PI / sqrtf(var);
        }
    }
    __syncthreads();

    const int lane = tid & 31;
    const int slot = tid >> 5;
    const long base = (long)blockIdx.x * ROWS_OUT;

    const float4 mu_n = p4[       lane];
    const float4 b_n  = p4[ 32 +  lane];
    const float4 c_n  = p4[ 64 +  lane];
    const float4 mu_a = p4[ 96 +  lane];
    const float4 b_a  = p4[128 +  lane];
    const float4 c_a  = p4[160 +  lane];

#define PDF_ACC(comp)                                                          \
    {                                                                          \
        float dn = x.comp - mu_n.comp;                                         \
        sn = fmaf(c_n.comp, __expf(b_n.comp * dn * dn), sn);                   \
        float da = x.comp - mu_a.comp;                                         \
        sa = fmaf(c_a.comp, __expf(b_a.comp * da * da), sa);                   \
    }

    // ---- phase B: scores for rows [base-7, base+ROWS_OUT] ----
    if (base >= 7 && base + ROWS_CMP - 7 <= n) {
        // interior fast path: no per-pass bounds checks (99.9% of blocks)
        const float4* ep = (const float4*)enc + (base - 7) * 32 + lane;
        #pragma unroll
        for (int p = 0; p < NPASS; ++p) {
            const int idx = p * 8 + slot;
            const float4 x = ep[idx * 32];
            float sn = 0.f, sa = 0.f;
            PDF_ACC(x) PDF_ACC(y) PDF_ACC(z) PDF_ACC(w)
            #pragma unroll
            for (int m = 16; m >= 1; m >>= 1) {
                sn += __shfl_xor(sn, m, 32);
                sa += __shfl_xor(sa, m, 32);
            }
            if (lane == 0) sc[idx] = make_float2(sn, sa);
        }
    } else {
        #pragma unroll
        for (int p = 0; p < NPASS; ++p) {
            const int idx = p * 8 + slot;
            const long g = base - 7 + idx;
            float sn = 0.f, sa = 0.f;
            if (g >= 0 && g < n) {
                const float4 x = ((const float4*)enc)[g * 32 + lane];
                PDF_ACC(x) PDF_ACC(y) PDF_ACC(z) PDF_ACC(w)
            }
            #pragma unroll
            for (int m = 16; m >= 1; m >>= 1) {
                sn += __shfl_xor(sn, m, 32);
                sa += __shfl_xor(sa, m, 32);
            }
            if (lane == 0) sc[idx] = make_float2(sn, sa);
        }
    }
#undef PDF_ACC
    __syncthreads();

    // ---- phase C: windowed scan + normalize (thread t -> row base+t) ----
    if (tid < ROWS_OUT) {
        const long r = base + tid;
        if (r < n) {
            const float inv_dim = 1.0f / 128.0f;
            float pn = 0.f, pa = 0.f;
            // sc[tid + k] holds s[r - 7 + k]; leading zero rows (r<7) reproduce
            // the reference's shorter window exactly (zeros are fixed points).
            #pragma unroll
            for (int k = 0; k < 8; ++k) {
                const float2 sv = sc[tid + k];
                pn = (pn + sv.x) * inv_dim;
                pa = (pa + sv.y) * inv_dim;
            }
            const float tot = pn + pa;
            out[r] = make_float2(pn / tot, pa / tot);
        }
    }
}

extern "C" void kernel_launch(void* const* d_in, const int* in_sizes, int n_in,
                              void* d_out, int out_size, void* d_ws, size_t ws_size,
                              hipStream_t stream) {
    const float* enc = (const float*)d_in[0];
    const float* nd  = (const float*)d_in[1];
    const float* ad  = (const float*)d_in[2];
    const int n_rows = in_sizes[0] / DIM;

    fused_kernel<<<(n_rows + ROWS_OUT - 1) / ROWS_OUT, 256, 0, stream>>>(
        enc, nd, ad, (float2*)d_out, n_rows);
}